// Round 16
// baseline (48.057 us; speedup 1.0000x reference)
//
#include <hip/hip_runtime.h>
#include <hip/hip_fp16.h>
#include <math.h>

// Padded LDS index for FFT scratch: injective for e in [0,256) -> [0,271)
#define PIDX(e) ((e) + ((e) >> 4))

// Wave-local "sync": waves own disjoint LDS slices; same-wave DS ops are
// processed in order by the LDS pipe, so we only need a COMPILER fence.
#define WAVE_SYNC()                          \
    do {                                     \
        __builtin_amdgcn_wave_barrier();     \
        asm volatile("" ::: "memory");       \
    } while (0)

__device__ __forceinline__ float2 cadd(float2 a, float2 b) { return {a.x + b.x, a.y + b.y}; }
__device__ __forceinline__ float2 csub(float2 a, float2 b) { return {a.x - b.x, a.y - b.y}; }
__device__ __forceinline__ float2 cmul(float2 a, float2 b) {
    return {a.x * b.x - a.y * b.y, a.x * b.y + a.y * b.x};
}
__device__ __forceinline__ float2 shfl64(float2 v, int src) {
    return {__shfl(v.x, src), __shfl(v.y, src)};
}

// Radix-4 butterfly (DIF): d0..d3 from c0..c3.
#define BFLY4(c0, c1, c2, c3, d0, d1, d2, d3)            \
    {                                                    \
        float2 sa = cadd(c0, c2);                        \
        float2 sb = csub(c0, c2);                        \
        float2 sc = cadd(c1, c3);                        \
        float2 sd = {(c1).y - (c3).y, (c3).x - (c1).x}; \
        d0 = cadd(sa, sc);                               \
        d1 = cadd(sb, sd);                               \
        d2 = csub(sa, sc);                               \
        d3 = csub(sb, sd);                               \
    }

// Per-lane twiddle set for one stage (constant across all FFTs of the kernel).
struct Tw {
    float2 w1, w2, w3;
};
__device__ __forceinline__ Tw make_tw(int idx) {
    const float ang = -0.024543692606170259f * (float)idx;  // -(2pi/256)*idx
    float sy, cx;
    __sincosf(ang, &sy, &cx);
    Tw tw;
    tw.w1 = {cx, sy};
    tw.w2 = cmul(tw.w1, tw.w1);
    tw.w3 = cmul(tw.w2, tw.w1);
    return tw;
}

// ---- Paired (2-FFT-in-flight) stages: A and B use disjoint buffers so each
// wave has two independent latency chains; every wait covers both FFTs. ----

// Stage 0 (stride-64 partners, within-lane): registers -> LDS (natural order).
__device__ __forceinline__ void stage0_pair(const float2* zA, const float2* zB, float2* XA,
                                            float2* XB, int t, const Tw& tw) {
    float2 a0, a1, a2, a3, b0, b1, b2, b3;
    BFLY4(zA[0], zA[1], zA[2], zA[3], a0, a1, a2, a3);
    BFLY4(zB[0], zB[1], zB[2], zB[3], b0, b1, b2, b3);
    const int ob = t << 2;
    XA[PIDX(ob)] = a0;
    XA[PIDX(ob + 1)] = cmul(tw.w1, a1);
    XA[PIDX(ob + 2)] = cmul(tw.w2, a2);
    XA[PIDX(ob + 3)] = cmul(tw.w3, a3);
    XB[PIDX(ob)] = b0;
    XB[PIDX(ob + 1)] = cmul(tw.w1, b1);
    XB[PIDX(ob + 2)] = cmul(tw.w2, b2);
    XB[PIDX(ob + 3)] = cmul(tw.w3, b3);
    WAVE_SYNC();
}

// Middle stage (SH=2 or 4), single buffer per FFT: reads are always
// {t, t+64, t+128, t+192}; read-all -> fence -> write-all (same-wave DS order).
template <int SH>
__device__ __forceinline__ void stage_mid_pair(float2* XA, float2* XB, int t, const Tw& tw) {
    float2 cA0 = XA[PIDX(t)], cA1 = XA[PIDX(t + 64)];
    float2 cA2 = XA[PIDX(t + 128)], cA3 = XA[PIDX(t + 192)];
    float2 cB0 = XB[PIDX(t)], cB1 = XB[PIDX(t + 64)];
    float2 cB2 = XB[PIDX(t + 128)], cB3 = XB[PIDX(t + 192)];
    WAVE_SYNC();
    float2 a0, a1, a2, a3, b0, b1, b2, b3;
    BFLY4(cA0, cA1, cA2, cA3, a0, a1, a2, a3);
    BFLY4(cB0, cB1, cB2, cB3, b0, b1, b2, b3);
    const int mm = 1 << SH;
    const int jj = t >> SH;
    const int kk = t & (mm - 1);
    const int ob = kk + 4 * mm * jj;
    XA[PIDX(ob)] = a0;
    XA[PIDX(ob + mm)] = cmul(tw.w1, a1);
    XA[PIDX(ob + 2 * mm)] = cmul(tw.w2, a2);
    XA[PIDX(ob + 3 * mm)] = cmul(tw.w3, a3);
    XB[PIDX(ob)] = b0;
    XB[PIDX(ob + mm)] = cmul(tw.w1, b1);
    XB[PIDX(ob + 2 * mm)] = cmul(tw.w2, b2);
    XB[PIDX(ob + 3 * mm)] = cmul(tw.w3, b3);
    WAVE_SYNC();
}

// Stage 3 (jj=0 -> identity twiddle): results to registers. d_q = Z[t+64q].
__device__ __forceinline__ void stage3_pair(float2* XA, float2* XB, int t, float2* dA,
                                            float2* dB) {
    float2 cA0 = XA[PIDX(t)], cA1 = XA[PIDX(t + 64)];
    float2 cA2 = XA[PIDX(t + 128)], cA3 = XA[PIDX(t + 192)];
    float2 cB0 = XB[PIDX(t)], cB1 = XB[PIDX(t + 64)];
    float2 cB2 = XB[PIDX(t + 128)], cB3 = XB[PIDX(t + 192)];
    WAVE_SYNC();  // reads complete before buffers are reused
    BFLY4(cA0, cA1, cA2, cA3, dA[0], dA[1], dA[2], dA[3]);
    BFLY4(cB0, cB1, cB2, cB3, dB[0], dB[1], dB[2], dB[3]);
}

// 16 strided dword loads: lane t gets element cols {t+64q} of rows r, r+1 for
// both inputs. Each instr reads 256B contiguous across the wave (coalesced).
__device__ __forceinline__ void load16(const float* __restrict__ abase,
                                       const float* __restrict__ sbase, int r, int t, float* a0,
                                       float* a1, float* s0, float* s1) {
#pragma unroll
    for (int q = 0; q < 4; ++q) {
        a0[q] = abase[(r << 8) + t + (q << 6)];
        a1[q] = abase[((r + 1) << 8) + t + (q << 6)];
        s0[q] = sbase[(r << 8) + t + (q << 6)];
        s1[q] = sbase[((r + 1) << 8) + t + (q << 6)];
    }
}

// Kernel 1: row FFTs of the real difference image, two rows per complex FFT,
// TWO packed FFTs in flight per wave. Output f16 spectra transposed
// [img][v][r], v in [0,128): v=0 packs (D[0],D[128]).
// grid = (16 row-chunks, nimg), block = 256 = 4 waves; each wave: one PAIR of
// packed FFTs (4 rows). 16 rows per block.
__global__ __launch_bounds__(256) void k_rowfft(const float* __restrict__ A,
                                                const float* __restrict__ P,
                                                const float* __restrict__ N,
                                                const int* __restrict__ negIdx,
                                                __half2* __restrict__ ws, int img0) {
    __shared__ float2 Xb[4][2][272];    // 17.4 KB (two buffers per wave)
    __shared__ __half2 outT[128 * 17];  // 8.7 KB, stride 17 -> conflict-free

    const int img = img0 + blockIdx.y;
    const int pair = img / 3;
    const int ch = img - pair * 3;
    int i, jn;
    const float* S;
    if (pair < 32) {  // anchor-positive pairs: j == i
        i = pair;
        jn = pair;
        S = P;
    } else {  // anchor-negative pairs: j = neg_idx[i][k]
        const int t2 = pair - 32;
        i = t2 >> 1;
        jn = negIdx[(i << 1) + (t2 & 1)];
        S = N;
    }
    const float* abase = A + ((size_t)(i * 3 + ch) << 16);
    const float* sbase = S + ((size_t)(jn * 3 + ch) << 16);

    const int tid = threadIdx.x;
    const int w = tid >> 6;   // wave id
    const int t = tid & 63;   // lane
    const int r0 = blockIdx.x * 16;

    // Hoisted per-lane twiddles (constant for every FFT in this kernel).
    const Tw tw0 = make_tw(t);
    const Tw tw1 = make_tw(t & ~3);
    const Tw tw2 = make_tw(t & ~15);
    const int ridx = (64 - t) & 63;  // reversal shuffle index

    // Issue ALL global loads up front (both FFTs' rows fly together).
    float a0A[4], a1A[4], s0A[4], s1A[4];
    float a0B[4], a1B[4], s0B[4], s1B[4];
    load16(abase, sbase, r0 + 4 * w, t, a0A, a1A, s0A, s1A);
    load16(abase, sbase, r0 + 4 * w + 2, t, a0B, a1B, s0B, s1B);

    float2 zA[4], zB[4];
#pragma unroll
    for (int q = 0; q < 4; ++q) {
        zA[q] = {a0A[q] - s0A[q], a1A[q] - s1A[q]};
        zB[q] = {a0B[q] - s0B[q], a1B[q] - s1B[q]};
    }
    float2* XA = Xb[w][0];
    float2* XB = Xb[w][1];
    stage0_pair(zA, zB, XA, XB, t, tw0);
    stage_mid_pair<2>(XA, XB, t, tw1);
    stage_mid_pair<4>(XA, XB, t, tw2);
    float2 dA[4], dB[4];  // d_q = Z[t + 64q]
    stage3_pair(XA, XB, t, dA, dB);

    // Hermitian unpack (register/shuffle only):
    //   D_r[v] = 0.5*(Z[v] + conj(Z[-v]));  D_r1[v] = -0.5i*(Z[v] - conj(Z[-v]))
#pragma unroll
    for (int f = 0; f < 2; ++f) {
        const float2* d = f ? dB : dA;
        const int slot = 4 * w + 2 * f;  // even row slot in [0,16)
        const float2 m3 = shfl64(d[3], ridx);  // Z[256-t] for t>=1
        const float2 m2 = shfl64(d[2], ridx);  // Z[192-t] for t>=1
        if (t == 0) {
            // v=0 packs (D_r[0], D_r[128]) = (Re/Im Z[0], Re/Im Z[128])
            outT[slot] = __floats2half2_rn(d[0].x, d[2].x);
            outT[slot + 1] = __floats2half2_rn(d[0].y, d[2].y);
        } else {
            outT[t * 17 + slot] =
                __floats2half2_rn(0.5f * (d[0].x + m3.x), 0.5f * (d[0].y - m3.y));
            outT[t * 17 + slot + 1] =
                __floats2half2_rn(0.5f * (d[0].y + m3.y), -0.5f * (d[0].x - m3.x));
        }
        {  // v = t + 64;  m = Z[192-t] (lane 0: Z[192] = own d3)
            const int v = t + 64;
            const float2 mm2 = (t == 0) ? d[3] : m2;
            outT[v * 17 + slot] =
                __floats2half2_rn(0.5f * (d[1].x + mm2.x), 0.5f * (d[1].y - mm2.y));
            outT[v * 17 + slot + 1] =
                __floats2half2_rn(0.5f * (d[1].y + mm2.y), -0.5f * (d[1].x - mm2.x));
        }
    }

    __syncthreads();  // all waves' outT slots complete

    // write [v][r0..r0+15] chunks: one float4 (4 half2) per thread per iter
    __half2* g = ws + (size_t)blockIdx.y * (128 * 256);
    for (int e = tid; e < 128 * 4; e += 256) {
        const int v = e >> 2, rl4 = (e & 3) << 2;
        float4 val;
        __half2* vp = (__half2*)&val;
#pragma unroll
        for (int k = 0; k < 4; ++k) vp[k] = outT[v * 17 + rl4 + k];
        *(float4*)(g + v * 256 + r0 + rl4) = val;
    }
}

// Kernel 2: column FFTs (complex 256-pt) + weighted magnitude sum, TWO
// columns in flight per wave. grid = (8, nimg), block = 256 = 4 waves; each
// wave: 2 sequential column-pairs with register prefetch of the second pair.
// v=0 is the packed real pair (col0, col128): weight 1; v>=1: weight 2.
__global__ __launch_bounds__(256) void k_colfft(const __half2* __restrict__ ws,
                                                float* __restrict__ partial, int img0) {
    __shared__ float2 Xb[4][2][272];  // 17.4 KB
    __shared__ float wsum[4];
    const int tid = threadIdx.x;
    const int w = tid >> 6, t = tid & 63;
    const int vbase = blockIdx.x * 16 + w * 4;  // [0,128)
    const __half2* gimg = ws + (size_t)blockIdx.y * (128 * 256);

    const Tw tw0 = make_tw(t);
    const Tw tw1 = make_tw(t & ~3);
    const Tw tw2 = make_tw(t & ~15);

    float2* XA = Xb[w][0];
    float2* XB = Xb[w][1];

    // Load pair 1 (cols vbase, vbase+1) and prefetch pair 2 (vbase+2, +3).
    __half2 cA[4], cB[4], nA[4], nB[4];
#pragma unroll
    for (int q = 0; q < 4; ++q) {
        cA[q] = gimg[(size_t)vbase * 256 + t + (q << 6)];
        cB[q] = gimg[(size_t)(vbase + 1) * 256 + t + (q << 6)];
        nA[q] = gimg[(size_t)(vbase + 2) * 256 + t + (q << 6)];
        nB[q] = gimg[(size_t)(vbase + 3) * 256 + t + (q << 6)];
    }

    float acc = 0.f;
    float2 zA[4], zB[4], dA[4], dB[4];

    // ---- pair 1 ----
#pragma unroll
    for (int q = 0; q < 4; ++q) {
        zA[q] = __half22float2(cA[q]);
        zB[q] = __half22float2(cB[q]);
    }
    stage0_pair(zA, zB, XA, XB, t, tw0);
    stage_mid_pair<2>(XA, XB, t, tw1);
    stage_mid_pair<4>(XA, XB, t, tw2);
    stage3_pair(XA, XB, t, dA, dB);
    if (vbase == 0) {  // wave-uniform rare path: col 0 needs W[-u]; LDS round trip
        XA[PIDX(t)] = dA[0];
        XA[PIDX(t + 64)] = dA[1];
        XA[PIDX(t + 128)] = dA[2];
        XA[PIDX(t + 192)] = dA[3];
        WAVE_SYNC();
        float ssum = 0.f;
#pragma unroll
        for (int q = 0; q < 4; ++q) {
            const int u = t + 64 * q;
            const float2 zu = XA[PIDX(u)];
            const float2 zm = XA[PIDX((256 - u) & 255)];
            // C_A[u] = 0.5(W[u]+conj(W[-u]));  C_B[u] = -0.5i(W[u]-conj(W[-u]))
            const float ax = 0.5f * (zu.x + zm.x), ay = 0.5f * (zu.y - zm.y);
            const float bx = 0.5f * (zu.y + zm.y), by = -0.5f * (zu.x - zm.x);
            ssum += sqrtf(ax * ax + ay * ay) + sqrtf(bx * bx + by * by);
        }
        acc += ssum;
        WAVE_SYNC();  // special reads done before pair-2 stage0 overwrites XA
    } else {
        acc += 2.f * (sqrtf(dA[0].x * dA[0].x + dA[0].y * dA[0].y) +
                      sqrtf(dA[1].x * dA[1].x + dA[1].y * dA[1].y) +
                      sqrtf(dA[2].x * dA[2].x + dA[2].y * dA[2].y) +
                      sqrtf(dA[3].x * dA[3].x + dA[3].y * dA[3].y));
    }
    acc += 2.f * (sqrtf(dB[0].x * dB[0].x + dB[0].y * dB[0].y) +
                  sqrtf(dB[1].x * dB[1].x + dB[1].y * dB[1].y) +
                  sqrtf(dB[2].x * dB[2].x + dB[2].y * dB[2].y) +
                  sqrtf(dB[3].x * dB[3].x + dB[3].y * dB[3].y));

    // ---- pair 2 ----
#pragma unroll
    for (int q = 0; q < 4; ++q) {
        zA[q] = __half22float2(nA[q]);
        zB[q] = __half22float2(nB[q]);
    }
    stage0_pair(zA, zB, XA, XB, t, tw0);
    stage_mid_pair<2>(XA, XB, t, tw1);
    stage_mid_pair<4>(XA, XB, t, tw2);
    stage3_pair(XA, XB, t, dA, dB);
    acc += 2.f * (sqrtf(dA[0].x * dA[0].x + dA[0].y * dA[0].y) +
                  sqrtf(dA[1].x * dA[1].x + dA[1].y * dA[1].y) +
                  sqrtf(dA[2].x * dA[2].x + dA[2].y * dA[2].y) +
                  sqrtf(dA[3].x * dA[3].x + dA[3].y * dA[3].y));
    acc += 2.f * (sqrtf(dB[0].x * dB[0].x + dB[0].y * dB[0].y) +
                  sqrtf(dB[1].x * dB[1].x + dB[1].y * dB[1].y) +
                  sqrtf(dB[2].x * dB[2].x + dB[2].y * dB[2].y) +
                  sqrtf(dB[3].x * dB[3].x + dB[3].y * dB[3].y));

#pragma unroll
    for (int off = 32; off; off >>= 1) acc += __shfl_down(acc, off);
    if (t == 0) wsum[w] = acc;
    __syncthreads();
    if (tid == 0) {
        const int img = img0 + blockIdx.y;
        partial[img * 8 + blockIdx.x] = wsum[0] + wsum[1] + wsum[2] + wsum[3];
    }
}

// partial layout [img][chunk=8], img-major: pair p's 3 images = 24 consecutive floats.
// pairSum[0..31] = sum|FFT(a-p)| per i;  pairSum[32 + 2i + k] = sum|FFT(a_i - n_j)|
__global__ void k_final(const float* __restrict__ partial, float* __restrict__ out) {
    __shared__ float ps[96];
    const int t = threadIdx.x;  // 128 threads
    if (t < 96) {
        float s = 0.f;
        const float* p = partial + t * 24;
        for (int e = 0; e < 24; ++e) s += p[e];
        ps[t] = s;
    }
    __syncthreads();
    if (t < 64) {  // wave 0: t = 2i+k
        const float inv = 1.f / 196608.f;  // mean over C*H*W
        const float dap = ps[t >> 1] * inv;
        const float dan = ps[32 + t] * inv + 1e-7f;
        float val = dap / dan;
#pragma unroll
        for (int off = 32; off; off >>= 1) val += __shfl_down(val, off);
        if (t == 0) out[0] = val * (1.f / 64.f);  // / (MULTI_N_NUM * B)
    }
}

extern "C" void kernel_launch(void* const* d_in, const int* in_sizes, int n_in,
                              void* d_out, int out_size, void* d_ws, size_t ws_size,
                              hipStream_t stream) {
    const float* A = (const float*)d_in[0];
    const float* P = (const float*)d_in[1];
    const float* N = (const float*)d_in[2];
    const int* negIdx = (const int*)d_in[3];

    float* partial = (float*)d_ws;  // 288*8 floats = 9216 B
    __half2* inter = (__half2*)((char*)d_ws + 40960);
    const size_t perImg = (size_t)128 * 256 * sizeof(__half2);  // 131072 B
    size_t avail = ws_size > 40960 ? ws_size - 40960 : 0;
    int cap = (int)(avail / perImg);
    if (cap > 288) cap = 288;
    if (cap < 1) cap = 1;  // last resort

    for (int img0 = 0; img0 < 288; img0 += cap) {
        const int nimg = (288 - img0 < cap) ? (288 - img0) : cap;
        dim3 g1(16, nimg);
        k_rowfft<<<g1, dim3(256), 0, stream>>>(A, P, N, negIdx, inter, img0);
        dim3 g2(8, nimg);
        k_colfft<<<g2, dim3(256), 0, stream>>>(inter, partial, img0);
    }
    k_final<<<1, 128, 0, stream>>>(partial, (float*)d_out);
}

// Round 18
// 46.091 us; speedup vs baseline: 1.0427x; 1.0427x over previous
//
#include <hip/hip_runtime.h>
#include <hip/hip_fp16.h>
#include <math.h>

// Padded LDS index for FFT scratch: injective for e in [0,256) -> [0,271)
#define PIDX(e) ((e) + ((e) >> 4))

// Wave-local "sync": waves own disjoint LDS slices; same-wave DS ops are
// processed in order by the LDS pipe, so we only need a COMPILER fence.
#define WAVE_SYNC()                          \
    do {                                     \
        __builtin_amdgcn_wave_barrier();     \
        asm volatile("" ::: "memory");       \
    } while (0)

__device__ __forceinline__ float2 cadd(float2 a, float2 b) { return {a.x + b.x, a.y + b.y}; }
__device__ __forceinline__ float2 csub(float2 a, float2 b) { return {a.x - b.x, a.y - b.y}; }
__device__ __forceinline__ float2 cmul(float2 a, float2 b) {
    return {a.x * b.x - a.y * b.y, a.x * b.y + a.y * b.x};
}
__device__ __forceinline__ float2 shfl64(float2 v, int src) {
    return {__shfl(v.x, src), __shfl(v.y, src)};
}

// Radix-4 butterfly (DIF): d0..d3 from c0..c3.
#define BFLY4(c0, c1, c2, c3, d0, d1, d2, d3)            \
    {                                                    \
        float2 sa = cadd(c0, c2);                        \
        float2 sb = csub(c0, c2);                        \
        float2 sc = cadd(c1, c3);                        \
        float2 sd = {(c1).y - (c3).y, (c3).x - (c1).x}; \
        d0 = cadd(sa, sc);                               \
        d1 = cadd(sb, sd);                               \
        d2 = csub(sa, sc);                               \
        d3 = csub(sb, sd);                               \
    }

// Per-lane twiddle set for one stage (constant across all FFTs of the kernel).
struct Tw {
    float2 w1, w2, w3;
};
__device__ __forceinline__ Tw make_tw(int idx) {
    const float ang = -0.024543692606170259f * (float)idx;  // -(2pi/256)*idx
    float sy, cx;
    __sincosf(ang, &sy, &cx);
    Tw tw;
    tw.w1 = {cx, sy};
    tw.w2 = cmul(tw.w1, tw.w1);
    tw.w3 = cmul(tw.w2, tw.w1);
    return tw;
}

// Stage 0 (stride-64 partners, within-lane): registers -> LDS (natural order).
__device__ __forceinline__ void fft_stage0(float2 z0, float2 z1, float2 z2, float2 z3, float2* X,
                                           int t, const Tw& tw) {
    float2 d0, d1, d2, d3;
    BFLY4(z0, z1, z2, z3, d0, d1, d2, d3);
    const int ob = t << 2;
    X[PIDX(ob)] = d0;
    X[PIDX(ob + 1)] = cmul(tw.w1, d1);
    X[PIDX(ob + 2)] = cmul(tw.w2, d2);
    X[PIDX(ob + 3)] = cmul(tw.w3, d3);
    WAVE_SYNC();
}

// Middle stage (s=1: SH=2, s=2: SH=4), single LDS buffer: reads are always
// {t, t+64, t+128, t+192}; read-all -> fence -> write-all (same-wave DS order).
template <int SH>
__device__ __forceinline__ void fft_stage_mid(float2* X, int t, const Tw& tw) {
    float2 c0 = X[PIDX(t)];
    float2 c1 = X[PIDX(t + 64)];
    float2 c2 = X[PIDX(t + 128)];
    float2 c3 = X[PIDX(t + 192)];
    WAVE_SYNC();
    float2 d0, d1, d2, d3;
    BFLY4(c0, c1, c2, c3, d0, d1, d2, d3);
    const int mm = 1 << SH;
    const int jj = t >> SH;
    const int kk = t & (mm - 1);
    const int ob = kk + 4 * mm * jj;
    X[PIDX(ob)] = d0;
    X[PIDX(ob + mm)] = cmul(tw.w1, d1);
    X[PIDX(ob + 2 * mm)] = cmul(tw.w2, d2);
    X[PIDX(ob + 3 * mm)] = cmul(tw.w3, d3);
    WAVE_SYNC();
}

// Stage 3 (jj=0 -> identity twiddle): keep the result in registers, WITH the
// trailing fence (single-buffer use: next stage0 reuses this buffer).
__device__ __forceinline__ void fft_stage3_reg(float2* X, int t, float2& d0, float2& d1,
                                               float2& d2, float2& d3) {
    float2 c0 = X[PIDX(t)];
    float2 c1 = X[PIDX(t + 64)];
    float2 c2 = X[PIDX(t + 128)];
    float2 c3 = X[PIDX(t + 192)];
    WAVE_SYNC();  // reads done before this buffer is overwritten by next stage0
    BFLY4(c0, c1, c2, c3, d0, d1, d2, d3);
}

// Stage 3 WITHOUT trailing fence: for alternating-buffer pipelines where the
// next stage0 targets a DIFFERENT buffer — lets the compiler schedule the next
// FFT's stage-0 VALU into this stage's lgkmcnt shadow.
__device__ __forceinline__ void fft_stage3_reg_nofence(float2* X, int t, float2& d0, float2& d1,
                                                       float2& d2, float2& d3) {
    float2 c0 = X[PIDX(t)];
    float2 c1 = X[PIDX(t + 64)];
    float2 c2 = X[PIDX(t + 128)];
    float2 c3 = X[PIDX(t + 192)];
    BFLY4(c0, c1, c2, c3, d0, d1, d2, d3);
}

// 16 strided dword loads: lane t gets element cols {t+64q} of rows r, r+1 for
// both inputs. Each instr reads 256B contiguous across the wave (coalesced).
__device__ __forceinline__ void load16(const float* __restrict__ abase,
                                       const float* __restrict__ sbase, int r, int t, float* a0,
                                       float* a1, float* s0, float* s1) {
#pragma unroll
    for (int q = 0; q < 4; ++q) {
        a0[q] = abase[(r << 8) + t + (q << 6)];
        a1[q] = abase[((r + 1) << 8) + t + (q << 6)];
        s0[q] = sbase[(r << 8) + t + (q << 6)];
        s1[q] = sbase[((r + 1) << 8) + t + (q << 6)];
    }
}

// Kernel 1 (identical to the proven 45.7 µs version): row FFTs, two real rows
// per complex FFT. Output f16 spectra transposed [img][v][r], v in [0,128):
// v=0 packs (D[0],D[128]). grid = (8, nimg), block = 256 = 4 waves; 4 packed
// FFTs per wave with register prefetch; stage0+stage3 in regs; hoisted twiddles.
__global__ __launch_bounds__(256) void k_rowfft(const float* __restrict__ A,
                                                const float* __restrict__ P,
                                                const float* __restrict__ N,
                                                const int* __restrict__ negIdx,
                                                __half2* __restrict__ ws, int img0) {
    __shared__ float2 Xb[4][272];       // 8.7 KB (single-buffer FFT)
    __shared__ __half2 outT[128 * 33];  // 16.9 KB, stride 33 -> conflict-free

    const int img = img0 + blockIdx.y;
    const int pair = img / 3;
    const int ch = img - pair * 3;
    int i, jn;
    const float* S;
    if (pair < 32) {  // anchor-positive pairs: j == i
        i = pair;
        jn = pair;
        S = P;
    } else {  // anchor-negative pairs: j = neg_idx[i][k]
        const int t2 = pair - 32;
        i = t2 >> 1;
        jn = negIdx[(i << 1) + (t2 & 1)];
        S = N;
    }
    const float* abase = A + ((size_t)(i * 3 + ch) << 16);
    const float* sbase = S + ((size_t)(jn * 3 + ch) << 16);

    const int tid = threadIdx.x;
    const int w = tid >> 6;   // wave id
    const int t = tid & 63;   // lane
    const int r0 = blockIdx.x * 32;

    const Tw tw0 = make_tw(t);
    const Tw tw1 = make_tw(t & ~3);
    const Tw tw2 = make_tw(t & ~15);
    const int ridx = (64 - t) & 63;  // reversal shuffle index

    float pa0[4], pa1[4], ps0[4], ps1[4];
    load16(abase, sbase, r0 + 2 * w, t, pa0, pa1, ps0, ps1);

    for (int it = 0; it < 4; ++it) {
        const int slot = 2 * (it * 4 + w);  // even row slot in [0,32)
        float2 z[4];
#pragma unroll
        for (int q = 0; q < 4; ++q) z[q] = {pa0[q] - ps0[q], pa1[q] - ps1[q]};
        // prefetch next iteration's rows; flies under the whole FFT
        if (it < 3) load16(abase, sbase, r0 + 2 * ((it + 1) * 4 + w), t, pa0, pa1, ps0, ps1);
        fft_stage0(z[0], z[1], z[2], z[3], Xb[w], t, tw0);
        fft_stage_mid<2>(Xb[w], t, tw1);
        fft_stage_mid<4>(Xb[w], t, tw2);
        float2 d0, d1, d2, d3;  // d_q = Z[t + 64q]
        fft_stage3_reg(Xb[w], t, d0, d1, d2, d3);
        // Hermitian unpack (register/shuffle only):
        //   D_r[v] = 0.5*(Z[v] + conj(Z[-v]));  D_r1[v] = -0.5i*(Z[v] - conj(Z[-v]))
        const float2 m3 = shfl64(d3, ridx);  // Z[256-t] for t>=1
        const float2 m2 = shfl64(d2, ridx);  // Z[192-t] for t>=1
        if (t == 0) {
            // v=0 packs (D_r[0], D_r[128]) = (Re/Im Z[0], Re/Im Z[128])
            outT[slot] = __floats2half2_rn(d0.x, d2.x);
            outT[slot + 1] = __floats2half2_rn(d0.y, d2.y);
        } else {
            outT[t * 33 + slot] = __floats2half2_rn(0.5f * (d0.x + m3.x), 0.5f * (d0.y - m3.y));
            outT[t * 33 + slot + 1] =
                __floats2half2_rn(0.5f * (d0.y + m3.y), -0.5f * (d0.x - m3.x));
        }
        {  // v = t + 64;  m = Z[192-t] (lane 0: Z[192] = own d3)
            const int v = t + 64;
            const float2 mm2 = (t == 0) ? d3 : m2;
            outT[v * 33 + slot] = __floats2half2_rn(0.5f * (d1.x + mm2.x), 0.5f * (d1.y - mm2.y));
            outT[v * 33 + slot + 1] =
                __floats2half2_rn(0.5f * (d1.y + mm2.y), -0.5f * (d1.x - mm2.x));
        }
        WAVE_SYNC();  // outT slot writes complete before Xb reuse next iter
    }

    __syncthreads();  // all waves' outT slots complete

    // write [v][r0..r0+31] chunks: one float4 (4 half2) per thread per iter
    __half2* g = ws + (size_t)blockIdx.y * (128 * 256);
    for (int e = tid; e < 128 * 8; e += 256) {
        const int v = e >> 3, rl4 = (e & 7) << 2;
        float4 val;
        __half2* vp = (__half2*)&val;
#pragma unroll
        for (int k = 0; k < 4; ++k) vp[k] = outT[v * 33 + rl4 + k];
        *(float4*)(g + v * 256 + r0 + rl4) = val;
    }
}

// Kernel 2: column FFTs + weighted magnitude sum, SKEWED pipeline: each wave
// owns 4 consecutive columns processed serially, but LDS buffers ALTERNATE
// (A,B,A,B) and stage-3 has no trailing fence — the next column's stage-0
// VALU schedules into the previous column's final LDS-read shadow.
// Same-buffer reuse is 2 FFTs (3 fences) away -> safe by same-wave DS order.
// grid = (8, nimg), block = 256 = 4 waves; register prefetch of next column.
// v=0 is the packed real pair (col0, col128): weight 1; v>=1: weight 2.
__global__ __launch_bounds__(256) void k_colfft(const __half2* __restrict__ ws,
                                                float* __restrict__ partial, int img0) {
    __shared__ float2 Xb[4][2][272];  // 17.4 KB (two alternating buffers/wave)
    __shared__ float wsum[4];
    const int tid = threadIdx.x;
    const int w = tid >> 6, t = tid & 63;
    const int vbase = blockIdx.x * 16 + w * 4;  // [0,128)
    const __half2* gimg = ws + (size_t)blockIdx.y * (128 * 256);

    const Tw tw0 = make_tw(t);
    const Tw tw1 = make_tw(t & ~3);
    const Tw tw2 = make_tw(t & ~15);

    float acc = 0.f;
    __half2 cur[4], nxt[4];
#pragma unroll
    for (int q = 0; q < 4; ++q) cur[q] = gimg[(size_t)vbase * 256 + t + (q << 6)];
#pragma unroll
    for (int j = 0; j < 4; ++j) {
        const int v = vbase + j;
        float2* X = Xb[w][j & 1];  // alternate buffers across columns
        if (j < 3) {
#pragma unroll
            for (int q = 0; q < 4; ++q) nxt[q] = gimg[(size_t)(v + 1) * 256 + t + (q << 6)];
        }
        float2 z[4];
#pragma unroll
        for (int q = 0; q < 4; ++q) z[q] = __half22float2(cur[q]);
        fft_stage0(z[0], z[1], z[2], z[3], X, t, tw0);
        fft_stage_mid<2>(X, t, tw1);
        fft_stage_mid<4>(X, t, tw2);
        float2 d0, d1, d2, d3;  // d_q = W[t + 64q]
        float ssum = 0.f;
        if (v == 0) {  // wave-uniform rare path (col 0 only): needs W[-u]
            fft_stage3_reg(X, t, d0, d1, d2, d3);
            X[PIDX(t)] = d0;
            X[PIDX(t + 64)] = d1;
            X[PIDX(t + 128)] = d2;
            X[PIDX(t + 192)] = d3;
            WAVE_SYNC();
#pragma unroll
            for (int q = 0; q < 4; ++q) {
                const int u = t + 64 * q;
                const float2 zu = X[PIDX(u)];
                const float2 zm = X[PIDX((256 - u) & 255)];
                // C_A[u] = 0.5(W[u]+conj(W[-u]));  C_B[u] = -0.5i(W[u]-conj(W[-u]))
                const float ax = 0.5f * (zu.x + zm.x), ay = 0.5f * (zu.y - zm.y);
                const float bx = 0.5f * (zu.y + zm.y), by = -0.5f * (zu.x - zm.x);
                ssum += sqrtf(ax * ax + ay * ay) + sqrtf(bx * bx + by * by);
            }
            WAVE_SYNC();  // special reads done before this buffer's next reuse
        } else {
            // no trailing fence: next column's stage0 (other buffer) may
            // schedule into this stage's lgkmcnt shadow
            fft_stage3_reg_nofence(X, t, d0, d1, d2, d3);
            ssum = 2.f * (sqrtf(d0.x * d0.x + d0.y * d0.y) + sqrtf(d1.x * d1.x + d1.y * d1.y) +
                          sqrtf(d2.x * d2.x + d2.y * d2.y) + sqrtf(d3.x * d3.x + d3.y * d3.y));
        }
        acc += ssum;
#pragma unroll
        for (int q = 0; q < 4; ++q) cur[q] = nxt[q];
    }
#pragma unroll
    for (int off = 32; off; off >>= 1) acc += __shfl_down(acc, off);
    if (t == 0) wsum[w] = acc;
    __syncthreads();
    if (tid == 0) {
        const int img = img0 + blockIdx.y;
        partial[img * 8 + blockIdx.x] = wsum[0] + wsum[1] + wsum[2] + wsum[3];
    }
}

// partial layout [img][chunk=8], img-major: pair p's 3 images = 24 consecutive floats.
// pairSum[0..31] = sum|FFT(a-p)| per i;  pairSum[32 + 2i + k] = sum|FFT(a_i - n_j)|
__global__ void k_final(const float* __restrict__ partial, float* __restrict__ out) {
    __shared__ float ps[96];
    const int t = threadIdx.x;  // 128 threads
    if (t < 96) {
        float s = 0.f;
        const float* p = partial + t * 24;
        for (int e = 0; e < 24; ++e) s += p[e];
        ps[t] = s;
    }
    __syncthreads();
    if (t < 64) {  // wave 0: t = 2i+k
        const float inv = 1.f / 196608.f;  // mean over C*H*W
        const float dap = ps[t >> 1] * inv;
        const float dan = ps[32 + t] * inv + 1e-7f;
        float val = dap / dan;
#pragma unroll
        for (int off = 32; off; off >>= 1) val += __shfl_down(val, off);
        if (t == 0) out[0] = val * (1.f / 64.f);  // / (MULTI_N_NUM * B)
    }
}

extern "C" void kernel_launch(void* const* d_in, const int* in_sizes, int n_in,
                              void* d_out, int out_size, void* d_ws, size_t ws_size,
                              hipStream_t stream) {
    const float* A = (const float*)d_in[0];
    const float* P = (const float*)d_in[1];
    const float* N = (const float*)d_in[2];
    const int* negIdx = (const int*)d_in[3];

    float* partial = (float*)d_ws;  // 288*8 floats = 9216 B
    __half2* inter = (__half2*)((char*)d_ws + 40960);
    const size_t perImg = (size_t)128 * 256 * sizeof(__half2);  // 131072 B
    size_t avail = ws_size > 40960 ? ws_size - 40960 : 0;
    int cap = (int)(avail / perImg);
    if (cap > 288) cap = 288;
    if (cap < 1) cap = 1;  // last resort

    for (int img0 = 0; img0 < 288; img0 += cap) {
        const int nimg = (288 - img0 < cap) ? (288 - img0) : cap;
        dim3 g1(8, nimg);
        k_rowfft<<<g1, dim3(256), 0, stream>>>(A, P, N, negIdx, inter, img0);
        dim3 g2(8, nimg);
        k_colfft<<<g2, dim3(256), 0, stream>>>(inter, partial, img0);
    }
    k_final<<<1, 128, 0, stream>>>(partial, (float*)d_out);
}

// Round 19
// 45.512 us; speedup vs baseline: 1.0559x; 1.0127x over previous
//
#include <hip/hip_runtime.h>
#include <hip/hip_fp16.h>
#include <math.h>

// Padded LDS index for FFT scratch: injective for e in [0,256) -> [0,271)
#define PIDX(e) ((e) + ((e) >> 4))

// Wave-local "sync": waves own disjoint LDS slices; same-wave DS ops are
// processed in order by the LDS pipe, so we only need a COMPILER fence.
#define WAVE_SYNC()                          \
    do {                                     \
        __builtin_amdgcn_wave_barrier();     \
        asm volatile("" ::: "memory");       \
    } while (0)

__device__ __forceinline__ float2 cadd(float2 a, float2 b) { return {a.x + b.x, a.y + b.y}; }
__device__ __forceinline__ float2 csub(float2 a, float2 b) { return {a.x - b.x, a.y - b.y}; }
__device__ __forceinline__ float2 cmul(float2 a, float2 b) {
    return {a.x * b.x - a.y * b.y, a.x * b.y + a.y * b.x};
}
__device__ __forceinline__ float2 shfl64(float2 v, int src) {
    return {__shfl(v.x, src), __shfl(v.y, src)};
}

// Radix-4 butterfly (DIF): d0..d3 from c0..c3.
#define BFLY4(c0, c1, c2, c3, d0, d1, d2, d3)            \
    {                                                    \
        float2 sa = cadd(c0, c2);                        \
        float2 sb = csub(c0, c2);                        \
        float2 sc = cadd(c1, c3);                        \
        float2 sd = {(c1).y - (c3).y, (c3).x - (c1).x}; \
        d0 = cadd(sa, sc);                               \
        d1 = cadd(sb, sd);                               \
        d2 = csub(sa, sc);                               \
        d3 = csub(sb, sd);                               \
    }

// Per-lane twiddle set for one stage (constant across all FFTs of the kernel).
struct Tw {
    float2 w1, w2, w3;
};
__device__ __forceinline__ Tw make_tw(int idx) {
    const float ang = -0.024543692606170259f * (float)idx;  // -(2pi/256)*idx
    float sy, cx;
    __sincosf(ang, &sy, &cx);
    Tw tw;
    tw.w1 = {cx, sy};
    tw.w2 = cmul(tw.w1, tw.w1);
    tw.w3 = cmul(tw.w2, tw.w1);
    return tw;
}

// Stage 0 (stride-64 partners, within-lane): registers -> LDS (natural order).
__device__ __forceinline__ void fft_stage0(float2 z0, float2 z1, float2 z2, float2 z3, float2* X,
                                           int t, const Tw& tw) {
    float2 d0, d1, d2, d3;
    BFLY4(z0, z1, z2, z3, d0, d1, d2, d3);
    const int ob = t << 2;
    X[PIDX(ob)] = d0;
    X[PIDX(ob + 1)] = cmul(tw.w1, d1);
    X[PIDX(ob + 2)] = cmul(tw.w2, d2);
    X[PIDX(ob + 3)] = cmul(tw.w3, d3);
    WAVE_SYNC();
}

// Middle stage (s=1: SH=2, s=2: SH=4), single LDS buffer: reads are always
// {t, t+64, t+128, t+192}; read-all -> fence -> write-all (same-wave DS order).
template <int SH>
__device__ __forceinline__ void fft_stage_mid(float2* X, int t, const Tw& tw) {
    float2 c0 = X[PIDX(t)];
    float2 c1 = X[PIDX(t + 64)];
    float2 c2 = X[PIDX(t + 128)];
    float2 c3 = X[PIDX(t + 192)];
    WAVE_SYNC();
    float2 d0, d1, d2, d3;
    BFLY4(c0, c1, c2, c3, d0, d1, d2, d3);
    const int mm = 1 << SH;
    const int jj = t >> SH;
    const int kk = t & (mm - 1);
    const int ob = kk + 4 * mm * jj;
    X[PIDX(ob)] = d0;
    X[PIDX(ob + mm)] = cmul(tw.w1, d1);
    X[PIDX(ob + 2 * mm)] = cmul(tw.w2, d2);
    X[PIDX(ob + 3 * mm)] = cmul(tw.w3, d3);
    WAVE_SYNC();
}

// Stage 3 (jj=0 -> identity twiddle): keep the result in registers.
// d_q = Z[t + 64q].
__device__ __forceinline__ void fft_stage3_reg(float2* X, int t, float2& d0, float2& d1,
                                               float2& d2, float2& d3) {
    float2 c0 = X[PIDX(t)];
    float2 c1 = X[PIDX(t + 64)];
    float2 c2 = X[PIDX(t + 128)];
    float2 c3 = X[PIDX(t + 192)];
    WAVE_SYNC();  // reads done before this buffer is overwritten by next stage0
    BFLY4(c0, c1, c2, c3, d0, d1, d2, d3);
}

// 16 strided dword loads: lane t gets element cols {t+64q} of rows r, r+1 for
// both inputs. Each instr reads 256B contiguous across the wave (coalesced).
__device__ __forceinline__ void load16(const float* __restrict__ abase,
                                       const float* __restrict__ sbase, int r, int t, float* a0,
                                       float* a1, float* s0, float* s1) {
#pragma unroll
    for (int q = 0; q < 4; ++q) {
        a0[q] = abase[(r << 8) + t + (q << 6)];
        a1[q] = abase[((r + 1) << 8) + t + (q << 6)];
        s0[q] = sbase[(r << 8) + t + (q << 6)];
        s1[q] = sbase[((r + 1) << 8) + t + (q << 6)];
    }
}

// Kernel 1: row FFTs of the real difference image, two rows per complex FFT.
// Output f16 spectra transposed [img][v][r], v in [0,128): v=0 packs (D[0],D[128]).
// grid = (8 row-chunks, nimg), block = 256 = 4 waves; 4 packed FFTs per wave,
// register prefetch, stage0+stage3 in registers, hoisted twiddles.
__global__ __launch_bounds__(256) void k_rowfft(const float* __restrict__ A,
                                                const float* __restrict__ P,
                                                const float* __restrict__ N,
                                                const int* __restrict__ negIdx,
                                                __half2* __restrict__ ws, int img0) {
    __shared__ float2 Xb[4][272];       // 8.7 KB (single-buffer FFT)
    __shared__ __half2 outT[128 * 33];  // 16.9 KB, stride 33 -> conflict-free

    const int img = img0 + blockIdx.y;
    const int pair = img / 3;
    const int ch = img - pair * 3;
    int i, jn;
    const float* S;
    if (pair < 32) {  // anchor-positive pairs: j == i
        i = pair;
        jn = pair;
        S = P;
    } else {  // anchor-negative pairs: j = neg_idx[i][k]
        const int t2 = pair - 32;
        i = t2 >> 1;
        jn = negIdx[(i << 1) + (t2 & 1)];
        S = N;
    }
    const float* abase = A + ((size_t)(i * 3 + ch) << 16);
    const float* sbase = S + ((size_t)(jn * 3 + ch) << 16);

    const int tid = threadIdx.x;
    const int w = tid >> 6;   // wave id
    const int t = tid & 63;   // lane
    const int r0 = blockIdx.x * 32;

    // Hoisted per-lane twiddles (constant for every FFT in this kernel).
    const Tw tw0 = make_tw(t);
    const Tw tw1 = make_tw(t & ~3);
    const Tw tw2 = make_tw(t & ~15);
    const int ridx = (64 - t) & 63;  // reversal shuffle index

    float pa0[4], pa1[4], ps0[4], ps1[4];
    load16(abase, sbase, r0 + 2 * w, t, pa0, pa1, ps0, ps1);

    for (int it = 0; it < 4; ++it) {
        const int slot = 2 * (it * 4 + w);  // even row slot in [0,32)
        float2 z[4];
#pragma unroll
        for (int q = 0; q < 4; ++q) z[q] = {pa0[q] - ps0[q], pa1[q] - ps1[q]};
        // prefetch next iteration's rows; flies under the whole FFT
        if (it < 3) load16(abase, sbase, r0 + 2 * ((it + 1) * 4 + w), t, pa0, pa1, ps0, ps1);
        fft_stage0(z[0], z[1], z[2], z[3], Xb[w], t, tw0);
        fft_stage_mid<2>(Xb[w], t, tw1);
        fft_stage_mid<4>(Xb[w], t, tw2);
        float2 d0, d1, d2, d3;  // d_q = Z[t + 64q]
        fft_stage3_reg(Xb[w], t, d0, d1, d2, d3);
        // Hermitian unpack (register/shuffle only):
        //   D_r[v] = 0.5*(Z[v] + conj(Z[-v]));  D_r1[v] = -0.5i*(Z[v] - conj(Z[-v]))
        const float2 m3 = shfl64(d3, ridx);  // Z[256-t] for t>=1
        const float2 m2 = shfl64(d2, ridx);  // Z[192-t] for t>=1
        if (t == 0) {
            // v=0 packs (D_r[0], D_r[128]) = (Re/Im Z[0], Re/Im Z[128])
            outT[slot] = __floats2half2_rn(d0.x, d2.x);
            outT[slot + 1] = __floats2half2_rn(d0.y, d2.y);
        } else {
            outT[t * 33 + slot] = __floats2half2_rn(0.5f * (d0.x + m3.x), 0.5f * (d0.y - m3.y));
            outT[t * 33 + slot + 1] =
                __floats2half2_rn(0.5f * (d0.y + m3.y), -0.5f * (d0.x - m3.x));
        }
        {  // v = t + 64;  m = Z[192-t] (lane 0: Z[192] = own d3)
            const int v = t + 64;
            const float2 mm2 = (t == 0) ? d3 : m2;
            outT[v * 33 + slot] = __floats2half2_rn(0.5f * (d1.x + mm2.x), 0.5f * (d1.y - mm2.y));
            outT[v * 33 + slot + 1] =
                __floats2half2_rn(0.5f * (d1.y + mm2.y), -0.5f * (d1.x - mm2.x));
        }
        WAVE_SYNC();  // outT slot writes complete before Xb reuse next iter
    }

    __syncthreads();  // all waves' outT slots complete

    // write [v][r0..r0+31] chunks: one float4 (4 half2) per thread per iter
    __half2* g = ws + (size_t)blockIdx.y * (128 * 256);
    for (int e = tid; e < 128 * 8; e += 256) {
        const int v = e >> 3, rl4 = (e & 7) << 2;
        float4 val;
        __half2* vp = (__half2*)&val;
#pragma unroll
        for (int k = 0; k < 4; ++k) vp[k] = outT[v * 33 + rl4 + k];
        *(float4*)(g + v * 256 + r0 + rl4) = val;
    }
}

// Kernel 2: column FFTs (complex 256-pt) + weighted magnitude sum.
// grid = (8, nimg), block = 256 = 4 waves; each wave owns 4 consecutive
// columns serially with register prefetch; stages 0 & 3 in registers,
// magnitudes own-lane (LDS-free) except the rare v==0 wave.
// v=0 is the packed real pair (col0, col128): weight 1; v>=1: weight 2.
__global__ __launch_bounds__(256) void k_colfft(const __half2* __restrict__ ws,
                                                float* __restrict__ partial, int img0) {
    __shared__ float2 Xb[4][272];  // 8.7 KB
    __shared__ float wsum[4];
    const int tid = threadIdx.x;
    const int w = tid >> 6, t = tid & 63;
    const int vbase = blockIdx.x * 16 + w * 4;  // [0,128)
    const __half2* gimg = ws + (size_t)blockIdx.y * (128 * 256);

    const Tw tw0 = make_tw(t);
    const Tw tw1 = make_tw(t & ~3);
    const Tw tw2 = make_tw(t & ~15);

    float acc = 0.f;
    __half2 cur[4], nxt[4];
#pragma unroll
    for (int q = 0; q < 4; ++q) cur[q] = gimg[(size_t)vbase * 256 + t + (q << 6)];
    for (int j = 0; j < 4; ++j) {
        const int v = vbase + j;
        if (j < 3) {
#pragma unroll
            for (int q = 0; q < 4; ++q) nxt[q] = gimg[(size_t)(v + 1) * 256 + t + (q << 6)];
        }
        float2 z[4];
#pragma unroll
        for (int q = 0; q < 4; ++q) z[q] = __half22float2(cur[q]);
        fft_stage0(z[0], z[1], z[2], z[3], Xb[w], t, tw0);
        fft_stage_mid<2>(Xb[w], t, tw1);
        fft_stage_mid<4>(Xb[w], t, tw2);
        float2 d0, d1, d2, d3;  // d_q = W[t + 64q]
        fft_stage3_reg(Xb[w], t, d0, d1, d2, d3);
        float ssum = 0.f;
        if (v == 0) {  // wave-uniform rare path: needs W[-u]; LDS round trip
            Xb[w][PIDX(t)] = d0;
            Xb[w][PIDX(t + 64)] = d1;
            Xb[w][PIDX(t + 128)] = d2;
            Xb[w][PIDX(t + 192)] = d3;
            WAVE_SYNC();
#pragma unroll
            for (int q = 0; q < 4; ++q) {
                const int u = t + 64 * q;
                const float2 zu = Xb[w][PIDX(u)];
                const float2 zm = Xb[w][PIDX((256 - u) & 255)];
                // C_A[u] = 0.5(W[u]+conj(W[-u]));  C_B[u] = -0.5i(W[u]-conj(W[-u]))
                const float ax = 0.5f * (zu.x + zm.x), ay = 0.5f * (zu.y - zm.y);
                const float bx = 0.5f * (zu.y + zm.y), by = -0.5f * (zu.x - zm.x);
                ssum += sqrtf(ax * ax + ay * ay) + sqrtf(bx * bx + by * by);
            }
        } else {
            ssum = 2.f * (sqrtf(d0.x * d0.x + d0.y * d0.y) + sqrtf(d1.x * d1.x + d1.y * d1.y) +
                          sqrtf(d2.x * d2.x + d2.y * d2.y) + sqrtf(d3.x * d3.x + d3.y * d3.y));
        }
        acc += ssum;
#pragma unroll
        for (int q = 0; q < 4; ++q) cur[q] = nxt[q];
        WAVE_SYNC();  // Xb fully consumed before next column's stage-0 writes
    }
#pragma unroll
    for (int off = 32; off; off >>= 1) acc += __shfl_down(acc, off);
    if (t == 0) wsum[w] = acc;
    __syncthreads();
    if (tid == 0) {
        const int img = img0 + blockIdx.y;
        partial[img * 8 + blockIdx.x] = wsum[0] + wsum[1] + wsum[2] + wsum[3];
    }
}

// partial layout [img][chunk=8], img-major: pair p's 3 images = 24 consecutive floats.
// pairSum[0..31] = sum|FFT(a-p)| per i;  pairSum[32 + 2i + k] = sum|FFT(a_i - n_j)|
__global__ void k_final(const float* __restrict__ partial, float* __restrict__ out) {
    __shared__ float ps[96];
    const int t = threadIdx.x;  // 128 threads
    if (t < 96) {
        float s = 0.f;
        const float* p = partial + t * 24;
        for (int e = 0; e < 24; ++e) s += p[e];
        ps[t] = s;
    }
    __syncthreads();
    if (t < 64) {  // wave 0: t = 2i+k
        const float inv = 1.f / 196608.f;  // mean over C*H*W
        const float dap = ps[t >> 1] * inv;
        const float dan = ps[32 + t] * inv + 1e-7f;
        float val = dap / dan;
#pragma unroll
        for (int off = 32; off; off >>= 1) val += __shfl_down(val, off);
        if (t == 0) out[0] = val * (1.f / 64.f);  // / (MULTI_N_NUM * B)
    }
}

extern "C" void kernel_launch(void* const* d_in, const int* in_sizes, int n_in,
                              void* d_out, int out_size, void* d_ws, size_t ws_size,
                              hipStream_t stream) {
    const float* A = (const float*)d_in[0];
    const float* P = (const float*)d_in[1];
    const float* N = (const float*)d_in[2];
    const int* negIdx = (const int*)d_in[3];

    float* partial = (float*)d_ws;  // 288*8 floats = 9216 B
    __half2* inter = (__half2*)((char*)d_ws + 40960);
    const size_t perImg = (size_t)128 * 256 * sizeof(__half2);  // 131072 B
    size_t avail = ws_size > 40960 ? ws_size - 40960 : 0;
    int cap = (int)(avail / perImg);
    if (cap > 288) cap = 288;
    if (cap < 1) cap = 1;  // last resort

    for (int img0 = 0; img0 < 288; img0 += cap) {
        const int nimg = (288 - img0 < cap) ? (288 - img0) : cap;
        dim3 g1(8, nimg);
        k_rowfft<<<g1, dim3(256), 0, stream>>>(A, P, N, negIdx, inter, img0);
        dim3 g2(8, nimg);
        k_colfft<<<g2, dim3(256), 0, stream>>>(inter, partial, img0);
    }
    k_final<<<1, 128, 0, stream>>>(partial, (float*)d_out);
}